// Round 2
// baseline (2424.387 us; speedup 1.0000x reference)
//
#include <hip/hip_runtime.h>

#define KS   21
#define HALO 10
#define TH   16              // 4 waves x 4 rows per thread
#define TW   256
#define R    4               // output rows per thread
#define PH   (TH + 2*HALO)   // 36
#define PW   276             // 256 + 20, rows 16B-aligned
#define HDIM 768

__device__ __forceinline__ int reflect_idx(int x, int n) {
    if (x < 0) x = -x;
    if (x >= n) x = 2 * n - 2 - x;
    return x;
}

__global__ __launch_bounds__(256, 3)
void blur_by_kernel(const float* __restrict__ in,
                    const float* __restrict__ kern,
                    float* __restrict__ out) {
    __shared__ float tile[PH * PW];   // 39.7 KB

    const int bx  = blockIdx.x;   // 0..2   col tile
    const int by  = blockIdx.y;   // 0..47  row tile
    const int bc  = blockIdx.z;   // b*3+c
    const int b   = bc / 3;
    const int tid = threadIdx.x;
    const int lane = tid & 63;
    const int w    = tid >> 6;    // wave id -> output rows R*w .. R*w+R-1

    const float* plane = in + (size_t)bc * (HDIM * HDIM);
    const int y0 = by * TH - HALO;
    const int x0 = bx * TW - HALO;

    for (int idx = tid; idx < PH * PW; idx += 256) {
        int r = idx / PW;
        int c = idx - r * PW;
        tile[idx] = plane[reflect_idx(y0 + r, HDIM) * HDIM + reflect_idx(x0 + c, HDIM)];
    }
    __syncthreads();

    const float* kbase = kern + b * (KS * KS);  // block-uniform -> s_load

    // ki-outer structure: one 21-weight kernel row feeds R*84 = 336 FMAs.
    // kw double-buffered (SGPR-resident), prefetched one ki ahead.
    // Input: sliding 4-row register window, slot = row % 4 (static via unroll).
    float  kw[2][KS];
    float4 win[4][6];
    float  acc[R][4] = {};
    const int colbase = lane * 4;
    const int row0    = w * R;    // this wave's base tile row

    #define KLOAD(kbuf, ki_)                                                   \
        {                                                                      \
            const float* kr = kbase + (ki_) * KS;                              \
            _Pragma("unroll")                                                  \
            for (int j = 0; j < KS; ++j) kw[kbuf][j] = kr[j];                  \
        }

    #define WINLOAD(slot, row_)                                                \
        {                                                                      \
            const float4* lr = (const float4*)&tile[(row0 + (row_)) * PW + colbase]; \
            _Pragma("unroll")                                                  \
            for (int j = 0; j < 6; ++j) win[slot][j] = lr[j];                  \
        }

    #define FMAROW(slot, kbuf, r)                                              \
        {                                                                      \
            const float* xs_ = (const float*)(win[slot]);                      \
            const float* kr_ = kw[kbuf];                                       \
            _Pragma("unroll")                                                  \
            for (int kj = 0; kj < KS; ++kj) {                                  \
                float kv = kr_[kj];                                            \
                _Pragma("unroll")                                              \
                for (int c = 0; c < 4; ++c)                                    \
                    acc[r][c] = fmaf(kv, xs_[kj + c], acc[r][c]);              \
            }                                                                  \
        }

    // ---- prologue: krow 0 + window rows 0..3 ----
    KLOAD(0, 0);
    WINLOAD(0, 0); WINLOAD(1, 1); WINLOAD(2, 2); WINLOAD(3, 3);

    // One step: ki = kb4 + j (kb4 % 4 == 0, so ki%4 == j%4, ki%2 == j%2).
    // Order: consume slot j first (frees it), then issue next-row + next-krow
    // loads (land before their first use ~336 FMAs later), then rows 1..3.
    #define STEP_PF(j)                                                         \
        {                                                                      \
            FMAROW((j) % 4,       (j) % 2, 0);                                 \
            WINLOAD((j) % 4,      kb4 + (j) + 4);                              \
            KLOAD(((j) + 1) % 2,  kb4 + (j) + 1);                              \
            FMAROW(((j) + 1) % 4, (j) % 2, 1);                                 \
            FMAROW(((j) + 2) % 4, (j) % 2, 2);                                 \
            FMAROW(((j) + 3) % 4, (j) % 2, 3);                                 \
        }

    // ---- main: ki = 0..19 ; prefetch row ki+4 (<=23, always valid) and
    //      krow ki+1 (<=20, always valid) -> no guards needed ----
    #pragma unroll 1
    for (int kb4 = 0; kb4 < 20; kb4 += 4) {
        STEP_PF(0)
        STEP_PF(1)
        STEP_PF(2)
        STEP_PF(3)
    }

    // ---- tail: ki = 20 -> kw[0], rows 20..23 in slots 0..3 ----
    FMAROW(0, 0, 0);
    FMAROW(1, 0, 1);
    FMAROW(2, 0, 2);
    FMAROW(3, 0, 3);

    float* oplane = out + (size_t)bc * (HDIM * HDIM);
    const int gx = bx * TW + colbase;
    const int gy = by * TH + w * R;
    #pragma unroll
    for (int r = 0; r < R; ++r) {
        float4 v = make_float4(acc[r][0], acc[r][1], acc[r][2], acc[r][3]);
        *(float4*)&oplane[(size_t)(gy + r) * HDIM + gx] = v;
    }
}

extern "C" void kernel_launch(void* const* d_in, const int* in_sizes, int n_in,
                              void* d_out, int out_size, void* d_ws, size_t ws_size,
                              hipStream_t stream) {
    const float* in   = (const float*)d_in[0];   // (16,3,768,768) fp32
    const float* kern = (const float*)d_in[1];   // (16,21,21) fp32
    float* out = (float*)d_out;

    dim3 grid(HDIM / TW, HDIM / TH, 16 * 3);     // 3 x 48 x 48
    dim3 block(256);
    blur_by_kernel<<<grid, block, 0, stream>>>(in, kern, out);
}

// Round 3
// 399.661 us; speedup vs baseline: 6.0661x; 6.0661x over previous
//
#include <hip/hip_runtime.h>

#define KS   21
#define HALO 10
#define TH   16              // 4 waves x 4 rows per thread
#define TW   256
#define R    4               // output rows per thread
#define PH   (TH + 2*HALO)   // 36
#define PW   276             // 256 + 20, rows 16B-aligned
#define HDIM 768
#define NPAIR 11             // ceil(21/2) weight pairs per kernel row

typedef float f32x2 __attribute__((ext_vector_type(2)));
typedef unsigned long long u64;

__device__ __forceinline__ int reflect_idx(int x, int n) {
    if (x < 0) x = -x;
    if (x >= n) x = 2 * n - 2 - x;
    return x;
}

// Repack kernel weights into 8B-aligned u64 pairs: kws[b][ki][j] = (k[2j], k[2j+1])
// so the main kernel's s_load_dwordx2 pairs are aligned and parity is compile-time.
__global__ void prep_kernel(const float* __restrict__ kern, u64* __restrict__ kws) {
    int i = blockIdx.x * 256 + threadIdx.x;      // 16*21*11 = 3696
    if (i >= 16 * KS * NPAIR) return;
    int j   = i % NPAIR;
    int row = i / NPAIR;                          // b*21 + ki
    const float* kr = kern + row * KS;
    union { float f[2]; u64 u; } p;
    p.f[0] = kr[2 * j];
    p.f[1] = (2 * j + 1 < KS) ? kr[2 * j + 1] : 0.0f;
    kws[i] = p.u;
}

__global__ __launch_bounds__(256, 3)
void blur_by_kernel(const float* __restrict__ in,
                    const u64* __restrict__ kws,
                    float* __restrict__ out) {
    __shared__ float tile[PH * PW];   // 39.7 KB

    const int bx  = blockIdx.x;   // 0..2   col tile
    const int by  = blockIdx.y;   // 0..47  row tile
    const int bc  = blockIdx.z;   // b*3+c
    const int b   = bc / 3;
    const int tid = threadIdx.x;
    const int lane = tid & 63;
    const int w    = tid >> 6;    // wave id -> output rows R*w .. R*w+3

    const float* plane = in + (size_t)bc * (HDIM * HDIM);
    const int y0 = by * TH - HALO;
    const int x0 = bx * TW - HALO;

    for (int idx = tid; idx < PH * PW; idx += 256) {
        int r = idx / PW;
        int c = idx - r * PW;
        tile[idx] = plane[reflect_idx(y0 + r, HDIM) * HDIM + reflect_idx(x0 + c, HDIM)];
    }
    __syncthreads();

    const u64* kb = kws + b * (KS * NPAIR);   // block-uniform -> s_load

    f32x2 acc[R][2] = {};   // acc[r][0]=(c0,c1), acc[r][1]=(c2,c3)
    f32x2 we[12];           // even pairs (x[2p], x[2p+1]) -- direct from b128 loads
    f32x2 wo[11];           // odd pairs  (x[2p+1], x[2p+2]) -- one pk_mov each
    const int colbase = lane * 4;

    // 6 ds_read_b128 -> 12 even pairs; 11 pk_mov (op_sel) -> odd pairs
    #define LOADROW(t)                                                         \
        {                                                                      \
            const float4* lrow = (const float4*)&tile[(w * R + (t)) * PW + colbase]; \
            _Pragma("unroll")                                                  \
            for (int j = 0; j < 6; ++j) {                                      \
                float4 v = lrow[j];                                            \
                we[2 * j]     = (f32x2){v.x, v.y};                             \
                we[2 * j + 1] = (f32x2){v.z, v.w};                             \
            }                                                                  \
            _Pragma("unroll")                                                  \
            for (int p = 0; p < 11; ++p)                                       \
                asm("v_pk_mov_b32 %0, %1, %2 op_sel:[1,0] op_sel_hi:[0,0]"     \
                    : "=v"(wo[p]) : "v"(we[p]), "v"(we[p + 1]));               \
        }

    // One kernel row (21 taps) against current window row, for output row r.
    // Weight comes from a uniform 8B-aligned SGPR pair; op_sel broadcasts the
    // correct half to both lanes of the pk_fma -> zero broadcast cost.
    #define FMAROW(r, ki)                                                      \
        {                                                                      \
            const u64* kp = kb + (ki) * NPAIR;                                 \
            _Pragma("unroll")                                                  \
            for (int kj = 0; kj < KS; ++kj) {                                  \
                u64 kv = kp[kj >> 1];                                          \
                f32x2 xa = (kj & 1) ? wo[kj >> 1]       : we[kj >> 1];         \
                f32x2 xb = (kj & 1) ? wo[(kj >> 1) + 1] : we[(kj >> 1) + 1];   \
                if (kj & 1) {                                                  \
                    asm("v_pk_fma_f32 %0, %1, %2, %0 op_sel:[0,1,0] op_sel_hi:[1,1,1]" \
                        : "+v"(acc[r][0]) : "v"(xa), "s"(kv));                 \
                    asm("v_pk_fma_f32 %0, %1, %2, %0 op_sel:[0,1,0] op_sel_hi:[1,1,1]" \
                        : "+v"(acc[r][1]) : "v"(xb), "s"(kv));                 \
                } else {                                                       \
                    asm("v_pk_fma_f32 %0, %1, %2, %0 op_sel:[0,0,0] op_sel_hi:[1,0,1]" \
                        : "+v"(acc[r][0]) : "v"(xa), "s"(kv));                 \
                    asm("v_pk_fma_f32 %0, %1, %2, %0 op_sel:[0,0,0] op_sel_hi:[1,0,1]" \
                        : "+v"(acc[r][1]) : "v"(xb), "s"(kv));                 \
                }                                                              \
            }                                                                  \
        }

    // ---- ramp: t = 0..2 (partial r validity, compile-time resolved) ----
    #pragma unroll
    for (int t = 0; t < 3; ++t) {
        LOADROW(t);
        #pragma unroll
        for (int r = 0; r < 4; ++r)
            if (t - r >= 0) FMAROW(r, t - r);
    }

    // ---- steady: t = 3..20, all 4 rows valid ----
    #pragma unroll 1
    for (int t = 3; t <= 20; ++t) {
        LOADROW(t);
        #pragma unroll
        for (int r = 0; r < 4; ++r)
            FMAROW(r, t - r);
    }

    // ---- drain: t = 21..23 ----
    #pragma unroll
    for (int t = 21; t < 24; ++t) {
        LOADROW(t);
        #pragma unroll
        for (int r = 0; r < 4; ++r)
            if (t - r <= 20) FMAROW(r, t - r);
    }

    float* oplane = out + (size_t)bc * (HDIM * HDIM);
    const int gx = bx * TW + colbase;
    const int gy = by * TH + w * R;
    #pragma unroll
    for (int r = 0; r < 4; ++r) {
        float4 v = make_float4(acc[r][0].x, acc[r][0].y, acc[r][1].x, acc[r][1].y);
        *(float4*)&oplane[(size_t)(gy + r) * HDIM + gx] = v;
    }
}

extern "C" void kernel_launch(void* const* d_in, const int* in_sizes, int n_in,
                              void* d_out, int out_size, void* d_ws, size_t ws_size,
                              hipStream_t stream) {
    const float* in   = (const float*)d_in[0];   // (16,3,768,768) fp32
    const float* kern = (const float*)d_in[1];   // (16,21,21) fp32
    float* out = (float*)d_out;
    u64* kws  = (u64*)d_ws;                      // 16*21*11*8 = 29.6 KB

    prep_kernel<<<dim3((16 * KS * NPAIR + 255) / 256), dim3(256), 0, stream>>>(kern, kws);

    dim3 grid(HDIM / TW, HDIM / TH, 16 * 3);     // 3 x 48 x 48
    dim3 block(256);
    blur_by_kernel<<<grid, block, 0, stream>>>(in, kws, out);
}